// Round 18
// baseline (311.031 us; speedup 1.0000x reference)
//
#include <hip/hip_runtime.h>
#include <hip/hip_bf16.h>
#include <math.h>

// SGConv: x = emb[x_indices]; 3 hops of D^-1/2 (A+I) D^-1/2; out = x3 @ W^T + b.
// z-space: z = dinv*x; hop: z' = dinv^2*(z[c] + sum_{r->c} z[r]); last hop dinv^1.
// LEDGER (verified r0-17): emb/w/b fp32, out fp32, ei contiguous (2,E),
// index widths runtime-classified, bf16 z validated (absmax 4.9e-4).
// r17->r18: (1) per-col ROW-SORTED edge lists (p4 LDS insertion sort) so all
// waves sweep z in the same global order -> per-XCD L2 working set shrinks
// (r12: FETCH 83MB/hop = 8x cross-XCD refetch of uniform-random gathers);
// (2) hop3 fused into MFMA linear (k_hop_lin): gather -> A-fragments in
// registers, kills 25MB z round-trip + one launch.

#define FLAG_MX 0
#define FLAG_ME 1
#define SH 9        // 512 cols per bucket
#define WC 512      // cols per bucket
#define CH 4096     // edges per P1/P3 block
#define RMASK 0x7FFFFFu
#define DCAP 48     // max degree for locality sort (skip-sort above; still correct)

using short8 = __attribute__((ext_vector_type(8))) short;
using f32x4 = __attribute__((ext_vector_type(4))) float;

__device__ inline int idx_at(const void* p, long long i, int mode) {
    switch (mode) {
        case 1: return (int)((const long long*)p)[i];
        case 2: return (int)((const float*)p)[i];
        case 3: return (int)((const double*)p)[i];
        default: return ((const int*)p)[i];
    }
}

// bf16 helpers (RNE pack, shift unpack)
__device__ inline unsigned short f2bf(float f) {
    union { float f; unsigned u; } v; v.f = f;
    unsigned r = v.u + 0x7FFFu + ((v.u >> 16) & 1u);
    return (unsigned short)(r >> 16);
}
__device__ inline float bflo(unsigned d) { union { unsigned u; float f; } v; v.u = d << 16; return v.f; }
__device__ inline float bfhi(unsigned d) { union { unsigned u; float f; } v; v.u = d & 0xFFFF0000u; return v.f; }
__device__ inline unsigned pk(float a, float b) {
    return (unsigned)f2bf(a) | ((unsigned)f2bf(b) << 16);
}

__device__ int detect_me_block(const void* ei, int n, int* sbuf) {
    int t = threadIdx.x;
    int oke = 15;
    const int* w = (const int*)ei;
    const long long* L = (const long long*)ei;
    const float* f = (const float*)ei;
    const double* d = (const double*)ei;
    for (int k = t; k < 2048; k += 256) {
        if (!((unsigned)w[k] < (unsigned)n)) oke &= ~1;
        long long lv = L[k];
        if (!(lv >= 0 && lv < (long long)n)) oke &= ~2;
        float fv = f[k];
        if (!(fv >= 0.f && fv < (float)n && fv == truncf(fv))) oke &= ~4;
        double dv = d[k];
        if (!(dv >= 0.0 && dv < (double)n && dv == trunc(dv))) oke &= ~8;
    }
    sbuf[t] = oke;
    __syncthreads();
    for (int st = 128; st; st >>= 1) {
        if (t < st) sbuf[t] &= sbuf[t + st];
        __syncthreads();
    }
    int r = sbuf[0];
    __syncthreads();
    return (r & 2) ? 1 : (r & 8) ? 3 : (r & 4) ? 2 : 0;
}

__device__ int detect_mx_block(const void* xidx, int* sbuf) {
    int t = threadIdx.x;
    int okx = 15;
    const int* w = (const int*)xidx;
    const long long* L = (const long long*)xidx;
    const float* f = (const float*)xidx;
    const double* d = (const double*)xidx;
    for (int k = t; k < 2048; k += 256) {
        if (w[k] != k) okx &= ~1;
        if (L[k] != (long long)k) okx &= ~2;
        if (!(f[k] == (float)k)) okx &= ~4;
        if (!(d[k] == (double)k)) okx &= ~8;
    }
    sbuf[t] = okx;
    __syncthreads();
    for (int st = 128; st; st >>= 1) {
        if (t < st) sbuf[t] &= sbuf[t + st];
        __syncthreads();
    }
    int r = sbuf[0];
    __syncthreads();
    return (r & 2) ? 1 : (r & 8) ? 3 : (r & 4) ? 2 : 0;
}

// P1: inline classify (block 0 publishes flags) + per-block bucket histogram
// -> bhist[b*NBLK + blk] (bucket-major).
__global__ void __launch_bounds__(256) k_p1(
        const void* __restrict__ ei, const void* __restrict__ xidx,
        long long E, int n, int NBUK, int NBLK,
        int* __restrict__ bhist, int* __restrict__ flags) {
    __shared__ int hist[256];
    __shared__ int sbuf[256];
    int t = threadIdx.x;
    int blk = blockIdx.x;
    int me = detect_me_block(ei, n, sbuf);
    if (blk == 0) {
        int mx = detect_mx_block(xidx, sbuf);
        if (t == 0) { flags[FLAG_ME] = me; flags[FLAG_MX] = mx; }
    }
    long long base = (long long)blk * CH;
    int cnt = (int)min((long long)CH, E - base);
    hist[t] = 0;
    __syncthreads();
    for (int i = t; i < cnt; i += 256) {
        int c = idx_at(ei, E + base + i, me);
        int b = min(c >> SH, NBUK - 1);
        atomicAdd(&hist[b], 1);
    }
    __syncthreads();
    if (t < NBUK) bhist[(size_t)t * NBLK + blk] = hist[t];
}

// P2a: per-bucket chunked LDS exclusive scan over block-counts (in place);
// gcount[b] = bucket total.
__global__ void __launch_bounds__(256) k_p2a(
        int* __restrict__ bhist, int* __restrict__ gcount, int NBLK) {
    __shared__ int s[256];
    int b = blockIdx.x;
    int t = threadIdx.x;
    int* row = bhist + (size_t)b * NBLK;
    int carry = 0;
    for (int base = 0; base < NBLK; base += 256) {
        int i = base + t;
        int v = (i < NBLK) ? row[i] : 0;
        s[t] = v;
        __syncthreads();
        for (int st = 1; st < 256; st <<= 1) {
            int add = (t >= st) ? s[t - st] : 0;
            __syncthreads();
            s[t] += add;
            __syncthreads();
        }
        if (i < NBLK) row[i] = carry + s[t] - v;  // exclusive
        int total = s[255];
        __syncthreads();
        carry += total;
    }
    if (t == 0) gcount[b] = carry;
}

// in-block exclusive scan of gcount (NBUK <= 256), 256-thread version.
__device__ void scan_gcount(const int* gcount, int NBUK, int* p, int* gb_ex) {
    int t = threadIdx.x;
    int v = (t < NBUK) ? gcount[t] : 0;
    p[t] = v;
    __syncthreads();
    for (int st = 1; st < 256; st <<= 1) {
        int add = (t >= st) ? p[t - st] : 0;
        __syncthreads();
        p[t] += add;
        __syncthreads();
    }
    gb_ex[t] = p[t] - v;
    __syncthreads();
}

// 512-thread version (threads >= 256 ride along through the syncs).
__device__ void scan_gcount_512(const int* gcount, int NBUK, int* p, int* gb_ex) {
    int t = threadIdx.x;
    int v = (t < 256) ? ((t < NBUK) ? gcount[t] : 0) : 0;
    if (t < 256) p[t] = v;
    __syncthreads();
    for (int st = 1; st < 256; st <<= 1) {
        int add = (t >= st && t < 256) ? p[t - st] : 0;
        __syncthreads();
        if (t < 256) p[t] += add;
        __syncthreads();
    }
    if (t < 256) gb_ex[t] = p[t] - v;
    __syncthreads();
}

// P3: block-local counting sort by bucket; write packed (r | clocal<<23)
// to bucket-major staging (4B/edge). Zero global atomics.
__global__ void __launch_bounds__(256) k_p3(
        const void* __restrict__ ei, long long E, int n, int NBUK, int NBLK,
        const int* __restrict__ bhist, const int* __restrict__ gcount,
        unsigned* __restrict__ gstag, const int* __restrict__ flags) {
    __shared__ int hist[256], lbase[256], rsv[256], lcur[256], s[256], gb[256];
    __shared__ unsigned stage[CH];
    int t = threadIdx.x;
    int blk = blockIdx.x;
    scan_gcount(gcount, NBUK, s, gb);
    long long base = (long long)blk * CH;
    int cnt = (int)min((long long)CH, E - base);
    int me = flags[FLAG_ME];
    hist[t] = 0;
    __syncthreads();
    for (int i = t; i < cnt; i += 256) {
        int c = idx_at(ei, E + base + i, me);
        atomicAdd(&hist[min(c >> SH, NBUK - 1)], 1);
    }
    __syncthreads();
    int v = hist[t];
    s[t] = v;
    __syncthreads();
    for (int st = 1; st < 256; st <<= 1) {
        int add = (t >= st) ? s[t - st] : 0;
        __syncthreads();
        s[t] += add;
        __syncthreads();
    }
    lbase[t] = s[t] - v;
    lcur[t] = s[t] - v;
    if (t < NBUK) rsv[t] = gb[t] + bhist[(size_t)t * NBLK + blk];
    __syncthreads();
    for (int i = t; i < cnt; i += 256) {
        long long e = base + i;
        int r = idx_at(ei, e, me);
        int c = idx_at(ei, E + e, me);
        int b = min(c >> SH, NBUK - 1);
        unsigned pkv = ((unsigned)r & RMASK) |
                       (((unsigned)(c - (b << SH)) & (WC - 1)) << 23);
        int slot = atomicAdd(&lcur[b], 1);
        stage[slot] = pkv;
    }
    __syncthreads();
    // slot i belongs to bucket b where lbase[b] <= i < lbase[b]+hist[b]
    for (int i = t; i < cnt; i += 256) {
        unsigned pkv = stage[i];
        int lo = 0, hi = NBUK - 1;
        while (lo < hi) {
            int mid = (lo + hi + 1) >> 1;
            if (lbase[mid] <= i) lo = mid; else hi = mid - 1;
        }
        gstag[rsv[lo] + (i - lbase[lo])] = pkv;
    }
}

// P4 (512 threads): one block per bucket: col histogram + scan -> off/dinv;
// rowidx placement; then LDS insertion-sort of each col's edge list by row
// (locality for the hop gathers; unsorted tail at deg>DCAP remains correct).
__global__ void __launch_bounds__(512) k_p4(
        const unsigned* __restrict__ gstag, const int* __restrict__ gcount,
        int* __restrict__ off, float* __restrict__ dinv,
        int* __restrict__ rowidx, int n, int NBUK) {
    __shared__ int hist[WC], lofs[WC], cur[WC], p[512], gb[256];
    __shared__ int sortbuf[512 * (DCAP + 1)];  // pad 49 breaks bank conflicts
    int t = threadIdx.x;  // 0..511
    int b = blockIdx.x;
    int cbase = b << SH;
    scan_gcount_512(gcount, NBUK, p, gb);
    int e0 = gb[b];
    int e1 = e0 + gcount[b];
    int cnt = e1 - e0;
    if (b == NBUK - 1 && t == 0) off[n] = e1;  // == E
    hist[t] = 0;
    __syncthreads();
    for (int i = t; i < cnt; i += 512) {
        atomicAdd(&hist[gstag[e0 + i] >> 23], 1);
    }
    __syncthreads();
    int v = hist[t];
    p[t] = v;
    __syncthreads();
    for (int st = 1; st < 512; st <<= 1) {
        int add = (t >= st) ? p[t - st] : 0;
        __syncthreads();
        p[t] += add;
        __syncthreads();
    }
    int excl = p[t] - v;
    lofs[t] = excl;
    cur[t] = excl;
    __syncthreads();
    int ncols = n - cbase;
    if (ncols < 0) ncols = 0;
    if (ncols > WC) ncols = WC;
    if (t < ncols) {
        off[cbase + t] = e0 + lofs[t];
        dinv[cbase + t] = rsqrtf((float)(hist[t] + 1));  // +1 self-loop
    }
    for (int i = t; i < cnt; i += 512) {
        unsigned pkv = gstag[e0 + i];
        int cl = (int)(pkv >> 23);
        int slot = atomicAdd(&cur[cl], 1);
        rowidx[e0 + slot] = (int)(pkv & RMASK);
    }
    __threadfence_block();
    __syncthreads();
    // per-col row-sort (one col per thread) in LDS
    if (t < ncols) {
        int deg = hist[t];
        if (deg > 1 && deg <= DCAP) {
            int base = e0 + lofs[t];
            int* loc = sortbuf + t * (DCAP + 1);
            for (int i = 0; i < deg; i++) loc[i] = rowidx[base + i];
            for (int i = 1; i < deg; i++) {
                int key = loc[i];
                int j = i - 1;
                while (j >= 0 && loc[j] > key) { loc[j + 1] = loc[j]; j--; }
                loc[j + 1] = key;
            }
            for (int i = 0; i < deg; i++) rowidx[base + i] = loc[i];
        }
    }
}

// z0: z[node] = emb[xidx[node]] * dinv[node], bf16 out; thread = 16B chunk.
__global__ void __launch_bounds__(256) k_z0(
        const void* __restrict__ xidx, const float4* __restrict__ emb4,
        const float* __restrict__ dinv, uint4* __restrict__ z, int n,
        const int* __restrict__ flags) {
    int i = blockIdx.x * 256 + threadIdx.x;
    if (i >= n * 8) return;
    int node = i >> 3, q = i & 7;
    int xi = idx_at(xidx, node, flags[FLAG_MX]);
    if ((unsigned)xi >= (unsigned)n) xi = 0;
    float d = dinv[node];
    float4 a = emb4[(long long)xi * 16 + q * 2];
    float4 b = emb4[(long long)xi * 16 + q * 2 + 1];
    uint4 o;
    o.x = pk(a.x * d, a.y * d);
    o.y = pk(a.z * d, a.w * d);
    o.z = pk(b.x * d, b.y * d);
    o.w = pk(b.z * d, b.w * d);
    z[(long long)node * 8 + q] = o;
}

__device__ inline void acc8(float* acc, uint4 s) {
    acc[0] += bflo(s.x); acc[1] += bfhi(s.x);
    acc[2] += bflo(s.y); acc[3] += bfhi(s.y);
    acc[4] += bflo(s.z); acc[5] += bfhi(s.z);
    acc[6] += bflo(s.w); acc[7] += bfhi(s.w);
}

// hop: 8 contiguous nodes per wave; lane = one 16B chunk (8 bf16).
// Inner loop unrolled x4 (r13-proven structure).
__global__ void __launch_bounds__(256) k_hop(
        const uint4* __restrict__ zin, uint4* __restrict__ zout,
        const float* __restrict__ dinv, const int* __restrict__ off,
        const int* __restrict__ rowidx, int n, int last) {
    int tid = blockIdx.x * 256 + threadIdx.x;
    int node = tid >> 3;
    int q = tid & 7;
    if (node >= n) return;
    float acc[8];
    {
        uint4 s = zin[(long long)node * 8 + q];  // self-loop
        acc[0] = bflo(s.x); acc[1] = bfhi(s.x);
        acc[2] = bflo(s.y); acc[3] = bfhi(s.y);
        acc[4] = bflo(s.z); acc[5] = bfhi(s.z);
        acc[6] = bflo(s.w); acc[7] = bfhi(s.w);
    }
    int e0 = off[node], e1 = off[node + 1];
    int e = e0;
    for (; e + 4 <= e1; e += 4) {
        int r0 = rowidx[e + 0];
        int r1 = rowidx[e + 1];
        int r2 = rowidx[e + 2];
        int r3 = rowidx[e + 3];
        uint4 s0 = zin[(long long)r0 * 8 + q];
        uint4 s1 = zin[(long long)r1 * 8 + q];
        uint4 s2 = zin[(long long)r2 * 8 + q];
        uint4 s3 = zin[(long long)r3 * 8 + q];
        acc8(acc, s0);
        acc8(acc, s1);
        acc8(acc, s2);
        acc8(acc, s3);
    }
    for (; e < e1; e++) {
        int r = rowidx[e];
        acc8(acc, zin[(long long)r * 8 + q]);
    }
    float d = dinv[node];
    float sc = last ? d : d * d;
    uint4 o;
    o.x = pk(acc[0] * sc, acc[1] * sc);
    o.y = pk(acc[2] * sc, acc[3] * sc);
    o.z = pk(acc[4] * sc, acc[5] * sc);
    o.w = pk(acc[6] * sc, acc[7] * sc);
    zout[(long long)node * 8 + q] = o;
}

// Fused hop3 + MFMA linear. Wave = one 16-node tile. Lane (col,quad):
// gathers chunks {quad, quad+4} of node=tile*16+col's rows, accumulates fp32,
// scales by dinv (last hop), packs A-fragments in registers, 8 MFMAs, stores.
__global__ void __launch_bounds__(256) k_hop_lin(
        const uint4* __restrict__ zin, const float* __restrict__ dinv,
        const int* __restrict__ off, const int* __restrict__ rowidx,
        const float* __restrict__ w, const float* __restrict__ bias,
        float* __restrict__ out, int n, int ntiles) {
    int lane = threadIdx.x & 63;
    int wv = threadIdx.x >> 6;
    int col = lane & 15, quad = lane >> 4;

    short8 bw[4][2];
#pragma unroll
    for (int tN = 0; tN < 4; tN++)
#pragma unroll
        for (int s = 0; s < 2; s++) {
            const float* src = w + (tN * 16 + col) * 64 + s * 32 + quad * 8;
            short8 vv;
#pragma unroll
            for (int j = 0; j < 8; j++) vv[j] = (short)f2bf(src[j]);
            bw[tN][s] = vv;
        }
    float bv[4];
#pragma unroll
    for (int tN = 0; tN < 4; tN++) bv[tN] = bias[tN * 16 + col];

    int tile = blockIdx.x * 4 + wv;
    if (tile >= ntiles) return;
    int node = tile * 16 + col;

    float acc[16];
#pragma unroll
    for (int j = 0; j < 16; j++) acc[j] = 0.f;
    float sc = 0.f;
    if (node < n) {
        uint4 sa = zin[(long long)node * 8 + quad];      // chunk quad
        uint4 sb = zin[(long long)node * 8 + quad + 4];  // chunk quad+4
        acc8(acc, sa);
        acc8(acc + 8, sb);
        int e0 = off[node], e1 = off[node + 1];
        int e = e0;
        for (; e + 4 <= e1; e += 4) {
            int r0 = rowidx[e + 0];
            int r1 = rowidx[e + 1];
            int r2 = rowidx[e + 2];
            int r3 = rowidx[e + 3];
            uint4 a0 = zin[(long long)r0 * 8 + quad];
            uint4 b0 = zin[(long long)r0 * 8 + quad + 4];
            uint4 a1 = zin[(long long)r1 * 8 + quad];
            uint4 b1 = zin[(long long)r1 * 8 + quad + 4];
            uint4 a2 = zin[(long long)r2 * 8 + quad];
            uint4 b2 = zin[(long long)r2 * 8 + quad + 4];
            uint4 a3 = zin[(long long)r3 * 8 + quad];
            uint4 b3 = zin[(long long)r3 * 8 + quad + 4];
            acc8(acc, a0); acc8(acc + 8, b0);
            acc8(acc, a1); acc8(acc + 8, b1);
            acc8(acc, a2); acc8(acc + 8, b2);
            acc8(acc, a3); acc8(acc + 8, b3);
        }
        for (; e < e1; e++) {
            int r = rowidx[e];
            uint4 sa2 = zin[(long long)r * 8 + quad];
            uint4 sb2 = zin[(long long)r * 8 + quad + 4];
            acc8(acc, sa2);
            acc8(acc + 8, sb2);
        }
        sc = dinv[node];  // last hop: dinv^1
    }
    short8 a0f, a1f;
#pragma unroll
    for (int j = 0; j < 8; j++) {
        a0f[j] = (short)f2bf(acc[j] * sc);
        a1f[j] = (short)f2bf(acc[8 + j] * sc);
    }
#pragma unroll
    for (int tN = 0; tN < 4; tN++) {
        f32x4 c = {bv[tN], bv[tN], bv[tN], bv[tN]};
        c = __builtin_amdgcn_mfma_f32_16x16x32_bf16(a0f, bw[tN][0], c, 0, 0, 0);
        c = __builtin_amdgcn_mfma_f32_16x16x32_bf16(a1f, bw[tN][1], c, 0, 0, 0);
#pragma unroll
        for (int r = 0; r < 4; r++) {
            int nd = tile * 16 + quad * 4 + r;
            if (nd < n) out[(size_t)nd * 64 + tN * 16 + col] = c[r];
        }
    }
}

extern "C" void kernel_launch(void* const* d_in, const int* in_sizes, int n_in,
                              void* d_out, int out_size, void* d_ws, size_t ws_size,
                              hipStream_t stream) {
    const void* xidx = d_in[0];
    const void* ei = d_in[1];
    const float* emb = (const float*)d_in[2];
    const float* w = (const float*)d_in[3];
    const float* b = (const float*)d_in[4];

    const int n = in_sizes[0];
    const long long E = in_sizes[1] / 2;
    int NBUK = (int)((n + WC - 1) >> SH);
    if (NBUK > 256) NBUK = 256;  // dataset: n=100k -> 196
    const int NBLK = (int)((E + CH - 1) / CH);

    char* p = (char*)d_ws;
    auto alloc = [&](size_t bytes) -> void* {
        void* r = (void*)p;
        p += (bytes + 255) & ~(size_t)255;
        return r;
    };
    int* flags = (int*)alloc(256);
    float* dinv = (float*)alloc((size_t)n * 4);
    int* off = (int*)alloc((size_t)(n + 1) * 4);
    int* gcount = (int*)alloc(257 * 4);
    int* bhist = (int*)alloc((size_t)NBLK * NBUK * 4);
    int* rowidx = (int*)alloc((size_t)E * 4);
    uint4* zA = (uint4*)alloc((size_t)n * 64 * 2);  // bf16 z (12.8 MB) in ws
    uint4* zS = (uint4*)d_out;                      // bf16 z in d_out 1st half

    // packed staging (4B/edge) in d_out's 2nd half (E*4 <= n*64*2 here)
    unsigned* gstag;
    if ((size_t)E * 4 <= (size_t)n * 64 * 2)
        gstag = (unsigned*)((char*)d_out + (size_t)n * 64 * 2);
    else
        gstag = (unsigned*)alloc((size_t)E * 4);

    k_p1<<<NBLK, 256, 0, stream>>>(ei, xidx, E, n, NBUK, NBLK, bhist, flags);
    k_p2a<<<NBUK, 256, 0, stream>>>(bhist, gcount, NBLK);
    k_p3<<<NBLK, 256, 0, stream>>>(ei, E, n, NBUK, NBLK, bhist, gcount, gstag, flags);
    k_p4<<<NBUK, 512, 0, stream>>>(gstag, gcount, off, dinv, rowidx, n, NBUK);

    const int gF = (n * 8 + 255) / 256;
    const int ntiles = (n + 15) / 16;
    const int gM = (ntiles + 3) / 4;

    // z0 -> zA(ws); hop1 zA->zS(d_out half); hop2 zS->zA; fused hop3+linear
    // zA -> out (never reads d_out; zS dead by then). Alias-free.
    k_z0<<<gF, 256, 0, stream>>>(xidx, (const float4*)emb, dinv, zA, n, flags);
    k_hop<<<gF, 256, 0, stream>>>(zA, zS, dinv, off, rowidx, n, 0);
    k_hop<<<gF, 256, 0, stream>>>(zS, zA, dinv, off, rowidx, n, 0);
    k_hop_lin<<<gM, 256, 0, stream>>>(zA, dinv, off, rowidx, w, b,
                                      (float*)d_out, n, ntiles);
}